// Round 13
// baseline (138.264 us; speedup 1.0000x reference)
//
#include <hip/hip_runtime.h>

// 5-layer MLP [B,64]->32->12->8->6->2, fp32 in/out.
// Layer 0 on matrix cores (v_mfma_f32_32x32x16_bf16, 3-pass truncated-bf16
// split); R10/R12-proven DMA staging (global_load_lds, R6 XOR swizzle,
// counted s_waitcnt vmcnt(4), wave-private LDS, no __syncthreads).
// R13: transpose reuses the spent chunk buffer (buf1) in two exec-masked
// passes -> 8KB LDS/wave. BLOCK=128 (2 waves), grid=2048 -> exactly
// 8 blocks/CU = 16 waves/CU, single dispatch round.

typedef __attribute__((ext_vector_type(8))) short short8;
typedef __attribute__((ext_vector_type(16))) float f32x16;
typedef __attribute__((ext_vector_type(4))) unsigned uint4v;
typedef __attribute__((address_space(3))) void* as3p;
typedef const __attribute__((address_space(1))) void* as1p;

#define BLOCK 128
#define NT 4   // 64-row tiles per wave

__device__ __forceinline__ unsigned fbits(float x) {
    return __builtin_bit_cast(unsigned, x);
}
__device__ __forceinline__ float asf(unsigned u) {
    return __builtin_bit_cast(float, u);
}
// (hi16(ub)<<16) | hi16(ua)  -- one v_perm_b32
__device__ __forceinline__ unsigned packhi(unsigned ua, unsigned ub) {
    return __builtin_amdgcn_perm(ub, ua, 0x07060302u);
}
// 8 floats -> 8 truncated bf16 (element j = k-index j)
__device__ __forceinline__ short8 mk_hi(const float* f) {
    uint4v w;
#pragma unroll
    for (int t = 0; t < 4; ++t)
        w[t] = packhi(fbits(f[2 * t]), fbits(f[2 * t + 1]));
    return __builtin_bit_cast(short8, w);
}
// 8 floats -> bf16 of the truncation residuals
__device__ __forceinline__ short8 mk_lo(const float* f) {
    uint4v w;
#pragma unroll
    for (int t = 0; t < 4; ++t) {
        const float la = f[2 * t]     - asf(fbits(f[2 * t])     & 0xFFFF0000u);
        const float lb = f[2 * t + 1] - asf(fbits(f[2 * t + 1]) & 0xFFFF0000u);
        w[t] = packhi(fbits(la), fbits(lb));
    }
    return __builtin_bit_cast(short8, w);
}
#define MFMA(A, B, C) __builtin_amdgcn_mfma_f32_32x32x16_bf16(A, B, C, 0, 0, 0)

template <int IN, int OUT, bool RELU>
__device__ __forceinline__ void layer(const float* __restrict__ W,
                                      const float* __restrict__ b,
                                      const float* h_in, float* h_out) {
#pragma unroll
    for (int o = 0; o < OUT; ++o) h_out[o] = b[o];
#pragma unroll
    for (int i = 0; i < IN; ++i) {
        const float v = h_in[i];
#pragma unroll
        for (int o = 0; o < OUT; ++o)
            h_out[o] = fmaf(v, W[i * OUT + o], h_out[o]);   // uniform -> s_load
    }
    if (RELU) {
#pragma unroll
        for (int o = 0; o < OUT; ++o) h_out[o] = fmaxf(h_out[o], 0.0f);
    }
}

__global__ __launch_bounds__(BLOCK, 4) void mlp_kernel(
        const float* __restrict__ x,
        const float* __restrict__ W0, const float* __restrict__ b0,
        const float* __restrict__ W1, const float* __restrict__ b1,
        const float* __restrict__ W2, const float* __restrict__ b2,
        const float* __restrict__ W3, const float* __restrict__ b3,
        const float* __restrict__ W4, const float* __restrict__ b4,
        float* __restrict__ out, int nrows) {
    extern __shared__ char lds[];
    const int t = threadIdx.x;
    const int wv = t >> 6;
    const int lane = t & 63;
    char* buf0 = lds + wv * 8192;   // 4KB chunk buffer (even chunks)
    char* buf1 = buf0 + 4096;       // 4KB chunk buffer (odd) + transpose reuse

    const long long row0 = ((long long)blockIdx.x * 2 + wv) * (NT * 64);
    const char* xbase = reinterpret_cast<const char*>(x + row0 * 64);

    // --- R6/R10-proven per-lane staging source offset (inverse swizzle).
    const int hh = lane >> 3;
    const int qq = (lane & 7) ^ hh;
    const int stage_off = (2 * hh + (qq >> 2)) * 256 + (qq & 3) * 16;

    // --- A-fragment LDS read offsets: unit u of row r lives at slot
    //     (u + 4*(r&1)) ^ ((r>>1)&7) within super-row r>>1.
    const int r0 = lane & 31;        // A row (rt0); rt1 = r0+32
    const int hA = lane >> 5;        // k-half: k = 8*hA + j
    auto lds_off = [](int r, int u) {
        const int R = r >> 1, p = r & 1;
        return R * 128 + (((u + 4 * p) ^ (R & 7)) << 4);
    };
    const int aoff0 = lds_off(r0, 2 * hA);
    const int aoff1 = lds_off(r0, 2 * hA + 1);
    const int aoff2 = lds_off(r0 + 32, 2 * hA);
    const int aoff3 = lds_off(r0 + 32, 2 * hA + 1);

    // --- B fragments (W0), built once, held in registers. Lane holds
    //     B[k = c*16 + 8*hA + j][col = lane&31], j = 0..7.
    const int colB = lane & 31;
    short8 B0h, B0l, B1h, B1l, B2h, B2l, B3h, B3l;
    {
        float wf[8];
#define LOADB(c, BH, BL)                                                \
        {                                                               \
            _Pragma("unroll")                                           \
            for (int j = 0; j < 8; ++j)                                 \
                wf[j] = W0[((c) * 16 + 8 * hA + j) * 32 + colB];        \
            BH = mk_hi(wf);                                             \
            BL = mk_lo(wf);                                             \
        }
        LOADB(0, B0h, B0l)
        LOADB(1, B1h, B1l)
        LOADB(2, B2h, B2l)
        LOADB(3, B3h, B3l)
#undef LOADB
    }
    const float vb0 = b0[colB];   // bias for this lane's D column

    // Stage global chunk gc (tile gc>>2, col-chunk gc&3) into buf.
    auto STAGE = [&](int gc, char* buf) {
        const char* s0 = xbase + (gc >> 2) * (64 * 256) + (gc & 3) * 64 +
                         stage_off;
#pragma unroll
        for (int k = 0; k < 4; ++k)
            __builtin_amdgcn_global_load_lds((as1p)(s0 + k * 4096),
                                             (as3p)(buf + k * 1024), 16, 0, 0);
    };

    STAGE(0, buf0);   // prologue

#pragma unroll 1
    for (int tt = 0; tt < NT; ++tt) {
        f32x16 accA, accB;
#pragma unroll
        for (int r = 0; r < 16; ++r) { accA[r] = vb0; accB[r] = vb0; }

#define CHUNK_BODY(CUR, BH, BL)                                            \
        {                                                                  \
            float fA[8], fB[8];                                            \
            const float4 q0 = *reinterpret_cast<const float4*>(CUR + aoff0); \
            const float4 q1 = *reinterpret_cast<const float4*>(CUR + aoff1); \
            const float4 q2 = *reinterpret_cast<const float4*>(CUR + aoff2); \
            const float4 q3 = *reinterpret_cast<const float4*>(CUR + aoff3); \
            fA[0]=q0.x; fA[1]=q0.y; fA[2]=q0.z; fA[3]=q0.w;                \
            fA[4]=q1.x; fA[5]=q1.y; fA[6]=q1.z; fA[7]=q1.w;                \
            fB[0]=q2.x; fB[1]=q2.y; fB[2]=q2.z; fB[3]=q2.w;                \
            fB[4]=q3.x; fB[5]=q3.y; fB[6]=q3.z; fB[7]=q3.w;                \
            const short8 Ah = mk_hi(fA), Al = mk_lo(fA);                   \
            const short8 Ch = mk_hi(fB), Cl = mk_lo(fB);                   \
            accA = MFMA(Ah, BH, accA);                                     \
            accA = MFMA(Al, BH, accA);                                     \
            accA = MFMA(Ah, BL, accA);                                     \
            accB = MFMA(Ch, BH, accB);                                     \
            accB = MFMA(Cl, BH, accB);                                     \
            accB = MFMA(Ch, BL, accB);                                     \
        }
#define PHASE(c, BH, BL)                                                   \
        {                                                                  \
            const int gc = tt * 4 + (c);                                   \
            char* cur = ((c) & 1) ? buf1 : buf0;                           \
            char* oth = ((c) & 1) ? buf0 : buf1;                           \
            if (gc + 1 < NT * 4) {                                         \
                STAGE(gc + 1, oth);                                        \
                asm volatile("s_waitcnt vmcnt(4)" ::: "memory");           \
            } else {                                                       \
                asm volatile("s_waitcnt vmcnt(0)" ::: "memory");           \
            }                                                              \
            __builtin_amdgcn_sched_barrier(0);                             \
            CHUNK_BODY(cur, BH, BL)                                        \
        }

        PHASE(0, B0h, B0l)
        PHASE(1, B1h, B1l)
        PHASE(2, B2h, B2l)
        PHASE(3, B3h, B3l)
#undef PHASE
#undef CHUNK_BODY

        // --- ReLU + transpose through the SPENT chunk buffer (buf1: cur at
        //     c=3, its ds_reads are complete via MFMA data-deps; the DMA in
        //     flight targets buf0). Two 4KB passes, exec-masked readback.
        //     D: col=lane&31, row = rt*32 + (reg&3) + 8*(reg>>2) + 4*hA.
        float xr[32];

        // Pass A: rows 0..31 (accA).
#pragma unroll
        for (int reg = 0; reg < 16; ++reg) {
            const int r1 = (reg & 3) + 8 * (reg >> 2) + 4 * hA;   // 0..31
            const int w1 = r1 * 128 + (((colB >> 2) ^ (r1 & 7)) << 4) +
                           (colB & 3) * 4;
            *reinterpret_cast<float*>(buf1 + w1) = fmaxf(accA[reg], 0.0f);
        }
        if (lane < 32) {
#pragma unroll
            for (int u = 0; u < 8; ++u) {
                const int slot = u ^ (lane & 7);
                const float4 qv = *reinterpret_cast<const float4*>(
                    buf1 + lane * 128 + slot * 16);
                xr[4 * u + 0] = qv.x; xr[4 * u + 1] = qv.y;
                xr[4 * u + 2] = qv.z; xr[4 * u + 3] = qv.w;
            }
        }
        asm volatile("s_waitcnt lgkmcnt(0)" ::: "memory");  // reads before WAR
        __builtin_amdgcn_sched_barrier(0);

        // Pass B: rows 32..63 (accB), rebased to the same 4KB.
#pragma unroll
        for (int reg = 0; reg < 16; ++reg) {
            const int r2 = (reg & 3) + 8 * (reg >> 2) + 4 * hA;   // (row-32)
            const int w2 = r2 * 128 + (((colB >> 2) ^ (r2 & 7)) << 4) +
                           (colB & 3) * 4;
            *reinterpret_cast<float*>(buf1 + w2) = fmaxf(accB[reg], 0.0f);
        }
        if (lane >= 32) {
            const int r = lane & 31;
#pragma unroll
            for (int u = 0; u < 8; ++u) {
                const int slot = u ^ (r & 7);
                const float4 qv = *reinterpret_cast<const float4*>(
                    buf1 + r * 128 + slot * 16);
                xr[4 * u + 0] = qv.x; xr[4 * u + 1] = qv.y;
                xr[4 * u + 2] = qv.z; xr[4 * u + 3] = qv.w;
            }
        }

        // Tail layers (next tile's chunk-0 DMA is in flight during these).
        float h1[12], h2[8], h3[6], h4[2];
        layer<32, 12, true>(W1, b1, xr, h1);
        layer<12, 8, true>(W2, b2, h1, h2);
        layer<8, 6, true>(W3, b3, h2, h3);
        layer<6, 2, false>(W4, b4, h3, h4);

        reinterpret_cast<float2*>(out)[row0 + tt * 64 + lane] =
            make_float2(h4[0], h4[1]);
    }
}

extern "C" void kernel_launch(void* const* d_in, const int* in_sizes, int n_in,
                              void* d_out, int out_size, void* d_ws, size_t ws_size,
                              hipStream_t stream) {
    const float* x  = (const float*)d_in[0];
    const float* W0 = (const float*)d_in[1];
    const float* b0 = (const float*)d_in[2];
    const float* W1 = (const float*)d_in[3];
    const float* b1 = (const float*)d_in[4];
    const float* W2 = (const float*)d_in[5];
    const float* b2 = (const float*)d_in[6];
    const float* W3 = (const float*)d_in[7];
    const float* b3 = (const float*)d_in[8];
    const float* W4 = (const float*)d_in[9];
    const float* b4 = (const float*)d_in[10];
    float* out = (float*)d_out;

    const int nrows = in_sizes[0] / 64;                 // 1,048,576
    const int rows_per_block = 2 * NT * 64;             // 512
    const int grid = nrows / rows_per_block;            // 2048 (exact)
    const size_t shmem = 2 * 8192;                      // 16 KiB/block

    mlp_kernel<<<grid, BLOCK, shmem, stream>>>(x, W0, b0, W1, b1, W2, b2,
                                               W3, b3, W4, b4, out, nrows);
}

// Round 14
// 66.883 us; speedup vs baseline: 2.0672x; 2.0672x over previous
//
#include <hip/hip_runtime.h>

// 5-layer MLP [B,64]->32->12->8->6->2, fp32 in/out.
// Layer 0 on matrix cores, computed TRANSPOSED: D' = W0^T (A) x x^T (B) via
// v_mfma_f32_32x32x16_bf16 (3-pass truncated-bf16 split). A- and B-fragments
// of 32x32x16 share the same per-lane indexing, so the R12-proven W0 and
// x-row fragments are reused verbatim, just swapped. D' lands with
// col = batch row = lane&31; the two feature halves (lane r / lane r+32)
// are aligned with ONE v_permlane32_swap_b32 per reg pair -> no LDS
// transpose at all. LDS/wave = 8KB (chunk double-buffer only) -> 16
// waves/CU. Staging = R10/R12-proven global_load_lds + R6 XOR swizzle +
// counted s_waitcnt vmcnt(4); wave-private LDS, no __syncthreads.
// Tail layers scalar fmaf (s_load weights, proven).

typedef __attribute__((ext_vector_type(8))) short short8;
typedef __attribute__((ext_vector_type(16))) float f32x16;
typedef __attribute__((ext_vector_type(4))) unsigned uint4v;
typedef __attribute__((address_space(3))) void* as3p;
typedef const __attribute__((address_space(1))) void* as1p;

#define BLOCK 64
#define NT 4   // 64-row tiles per wave

__device__ __forceinline__ unsigned fbits(float x) {
    return __builtin_bit_cast(unsigned, x);
}
__device__ __forceinline__ float asf(unsigned u) {
    return __builtin_bit_cast(float, u);
}
// (hi16(ub)<<16) | hi16(ua)  -- one v_perm_b32
__device__ __forceinline__ unsigned packhi(unsigned ua, unsigned ub) {
    return __builtin_amdgcn_perm(ub, ua, 0x07060302u);
}
// 8 floats -> 8 truncated bf16 (element j = k-index j)
__device__ __forceinline__ short8 mk_hi(const float* f) {
    uint4v w;
#pragma unroll
    for (int t = 0; t < 4; ++t)
        w[t] = packhi(fbits(f[2 * t]), fbits(f[2 * t + 1]));
    return __builtin_bit_cast(short8, w);
}
// 8 floats -> bf16 of the truncation residuals
__device__ __forceinline__ short8 mk_lo(const float* f) {
    uint4v w;
#pragma unroll
    for (int t = 0; t < 4; ++t) {
        const float la = f[2 * t]     - asf(fbits(f[2 * t])     & 0xFFFF0000u);
        const float lb = f[2 * t + 1] - asf(fbits(f[2 * t + 1]) & 0xFFFF0000u);
        w[t] = packhi(fbits(la), fbits(lb));
    }
    return __builtin_bit_cast(short8, w);
}
#define MFMA(A, B, C) __builtin_amdgcn_mfma_f32_32x32x16_bf16(A, B, C, 0, 0, 0)

template <int IN, int OUT, bool RELU>
__device__ __forceinline__ void layer(const float* __restrict__ W,
                                      const float* __restrict__ b,
                                      const float* h_in, float* h_out) {
#pragma unroll
    for (int o = 0; o < OUT; ++o) h_out[o] = b[o];
#pragma unroll
    for (int i = 0; i < IN; ++i) {
        const float v = h_in[i];
#pragma unroll
        for (int o = 0; o < OUT; ++o)
            h_out[o] = fmaf(v, W[i * OUT + o], h_out[o]);   // uniform -> s_load
    }
    if (RELU) {
#pragma unroll
        for (int o = 0; o < OUT; ++o) h_out[o] = fmaxf(h_out[o], 0.0f);
    }
}

__global__ __launch_bounds__(BLOCK, 4) void mlp_kernel(
        const float* __restrict__ x,
        const float* __restrict__ W0, const float* __restrict__ b0,
        const float* __restrict__ W1, const float* __restrict__ b1,
        const float* __restrict__ W2, const float* __restrict__ b2,
        const float* __restrict__ W3, const float* __restrict__ b3,
        const float* __restrict__ W4, const float* __restrict__ b4,
        float* __restrict__ out, int nrows) {
    extern __shared__ char lds[];
    char* buf0 = lds;            // 4KB chunk buffer (even chunks)
    char* buf1 = lds + 4096;     // 4KB chunk buffer (odd chunks)

    const int lane = threadIdx.x;          // 1 wave per block
    const long long row0 = (long long)blockIdx.x * (NT * 64);
    const char* xbase = reinterpret_cast<const char*>(x + row0 * 64);

    // --- R6/R10-proven per-lane staging source offset (inverse swizzle).
    const int hh = lane >> 3;
    const int qq = (lane & 7) ^ hh;
    const int stage_off = (2 * hh + (qq >> 2)) * 256 + (qq & 3) * 16;

    // --- x-fragment LDS read offsets (B operand): lane holds
    //     x[row = lane&31][k = 16c + 8*hA + j] (and row+32 for accB).
    const int r0 = lane & 31;
    const int hA = lane >> 5;
    auto lds_off = [](int r, int u) {
        const int R = r >> 1, p = r & 1;
        return R * 128 + (((u + 4 * p) ^ (R & 7)) << 4);
    };
    const int aoff0 = lds_off(r0, 2 * hA);
    const int aoff1 = lds_off(r0, 2 * hA + 1);
    const int aoff2 = lds_off(r0 + 32, 2 * hA);
    const int aoff3 = lds_off(r0 + 32, 2 * hA + 1);

    // --- W0^T fragments (A operand), built once, held in registers.
    //     A[row = o = lane&31][k = 16c + 8*hA + j] = W0[k][o].
    const int colB = lane & 31;
    short8 W0h_, W0l_, W1h_, W1l_, W2h_, W2l_, W3h_, W3l_;
    {
        float wf[8];
#define LOADB(c, BH, BL)                                                \
        {                                                               \
            _Pragma("unroll")                                           \
            for (int j = 0; j < 8; ++j)                                 \
                wf[j] = W0[((c) * 16 + 8 * hA + j) * 32 + colB];        \
            BH = mk_hi(wf);                                             \
            BL = mk_lo(wf);                                             \
        }
        LOADB(0, W0h_, W0l_)
        LOADB(1, W1h_, W1l_)
        LOADB(2, W2h_, W2l_)
        LOADB(3, W3h_, W3l_)
#undef LOADB
    }

    // Stage global chunk gc (tile gc>>2, col-chunk gc&3) into buf.
    auto STAGE = [&](int gc, char* buf) {
        const char* s0 = xbase + (gc >> 2) * (64 * 256) + (gc & 3) * 64 +
                         stage_off;
#pragma unroll
        for (int k = 0; k < 4; ++k)
            __builtin_amdgcn_global_load_lds((as1p)(s0 + k * 4096),
                                             (as3p)(buf + k * 1024), 16, 0, 0);
    };

    STAGE(0, buf0);   // prologue

#pragma unroll 1
    for (int tt = 0; tt < NT; ++tt) {
        f32x16 accA, accB;   // D'[o][r]: cols r = batch rows (accA: 0-31)
#pragma unroll
        for (int r = 0; r < 16; ++r) { accA[r] = 0.0f; accB[r] = 0.0f; }

#define CHUNK_BODY(CUR, WH, WL)                                            \
        {                                                                  \
            float fA[8], fB[8];                                            \
            const float4 q0 = *reinterpret_cast<const float4*>(CUR + aoff0); \
            const float4 q1 = *reinterpret_cast<const float4*>(CUR + aoff1); \
            const float4 q2 = *reinterpret_cast<const float4*>(CUR + aoff2); \
            const float4 q3 = *reinterpret_cast<const float4*>(CUR + aoff3); \
            fA[0]=q0.x; fA[1]=q0.y; fA[2]=q0.z; fA[3]=q0.w;                \
            fA[4]=q1.x; fA[5]=q1.y; fA[6]=q1.z; fA[7]=q1.w;                \
            fB[0]=q2.x; fB[1]=q2.y; fB[2]=q2.z; fB[3]=q2.w;                \
            fB[4]=q3.x; fB[5]=q3.y; fB[6]=q3.z; fB[7]=q3.w;                \
            const short8 Xh = mk_hi(fA), Xl = mk_lo(fA);                   \
            const short8 Yh = mk_hi(fB), Yl = mk_lo(fB);                   \
            accA = MFMA(WH, Xh, accA);                                     \
            accA = MFMA(WL, Xh, accA);                                     \
            accA = MFMA(WH, Xl, accA);                                     \
            accB = MFMA(WH, Yh, accB);                                     \
            accB = MFMA(WL, Yh, accB);                                     \
            accB = MFMA(WH, Yl, accB);                                     \
        }
#define PHASE(c, WH, WL)                                                   \
        {                                                                  \
            const int gc = tt * 4 + (c);                                   \
            char* cur = ((c) & 1) ? buf1 : buf0;                           \
            char* oth = ((c) & 1) ? buf0 : buf1;                           \
            if (gc + 1 < NT * 4) {                                         \
                STAGE(gc + 1, oth);                                        \
                asm volatile("s_waitcnt vmcnt(4)" ::: "memory");           \
            } else {                                                       \
                asm volatile("s_waitcnt vmcnt(0)" ::: "memory");           \
            }                                                              \
            __builtin_amdgcn_sched_barrier(0);                             \
            CHUNK_BODY(cur, WH, WL)                                        \
        }

        PHASE(0, W0h_, W0l_)
        PHASE(1, W1h_, W1l_)
        PHASE(2, W2h_, W2l_)
        PHASE(3, W3h_, W3l_)
#undef PHASE
#undef CHUNK_BODY

        // --- Align feature halves with permlane32_swap (a.hi <-> b.lo):
        //     after swap, a[reg] = h0[myrow][f0], b[reg] = h0[myrow][f0+4],
        //     f0 = (reg&3) + 8*(reg>>2), for EVERY lane (myrow = row0+tt*64
        //     + lane). Bias + ReLU applied in-register. No LDS transpose.
        float xr[32];
#pragma unroll
        for (int reg = 0; reg < 16; ++reg) {
            float a = accA[reg];
            float b = accB[reg];
            asm("v_permlane32_swap_b32 %0, %1" : "+v"(a), "+v"(b));
            const int f0 = (reg & 3) + 8 * (reg >> 2);
            xr[f0]     = fmaxf(a + b0[f0],     0.0f);
            xr[f0 + 4] = fmaxf(b + b0[f0 + 4], 0.0f);
        }

        // Tail layers (next tile's chunk-0 DMA is in flight during these).
        float h1[12], h2[8], h3[6], h4[2];
        layer<32, 12, true>(W1, b1, xr, h1);
        layer<12, 8, true>(W2, b2, h1, h2);
        layer<8, 6, true>(W3, b3, h2, h3);
        layer<6, 2, false>(W4, b4, h3, h4);

        reinterpret_cast<float2*>(out)[row0 + tt * 64 + lane] =
            make_float2(h4[0], h4[1]);
    }
}

extern "C" void kernel_launch(void* const* d_in, const int* in_sizes, int n_in,
                              void* d_out, int out_size, void* d_ws, size_t ws_size,
                              hipStream_t stream) {
    const float* x  = (const float*)d_in[0];
    const float* W0 = (const float*)d_in[1];
    const float* b0 = (const float*)d_in[2];
    const float* W1 = (const float*)d_in[3];
    const float* b1 = (const float*)d_in[4];
    const float* W2 = (const float*)d_in[5];
    const float* b2 = (const float*)d_in[6];
    const float* W3 = (const float*)d_in[7];
    const float* b3 = (const float*)d_in[8];
    const float* W4 = (const float*)d_in[9];
    const float* b4 = (const float*)d_in[10];
    float* out = (float*)d_out;

    const int nrows = in_sizes[0] / 64;                 // 1,048,576
    const int rows_per_block = NT * 64;                 // 256
    const int grid = nrows / rows_per_block;            // 4096 (exact)
    const size_t shmem = 8192;                          // 2 x 4KB dbuf only

    mlp_kernel<<<grid, BLOCK, shmem, stream>>>(x, W0, b0, W1, b1, W2, b2,
                                               W3, b3, W4, b4, out, nrows);
}

// Round 15
// 66.827 us; speedup vs baseline: 2.0690x; 1.0008x over previous
//
#include <hip/hip_runtime.h>

// 5-layer MLP [B,64]->32->12->8->6->2, fp32 in/out.
// Layer 0 on matrix cores, computed TRANSPOSED: D' = W0^T (A) x x^T (B) via
// v_mfma_f32_32x32x16_bf16 (3-pass truncated-bf16 split). A- and B-fragments
// of 32x32x16 share the same per-lane indexing, so the R12-proven W0 and
// x-row fragments are reused verbatim, just swapped. D' lands with
// col = batch row = lane&31; the two feature halves (lane r / lane r+32)
// are aligned with ONE v_permlane32_swap_b32 per reg pair -> no LDS
// transpose at all. LDS/wave = 8KB (chunk double-buffer only) -> 16
// waves/CU. Staging = R10/R12-proven global_load_lds + R6 XOR swizzle +
// counted s_waitcnt vmcnt(4); wave-private LDS, no __syncthreads.
// Tail layers scalar fmaf (s_load weights, proven).

typedef __attribute__((ext_vector_type(8))) short short8;
typedef __attribute__((ext_vector_type(16))) float f32x16;
typedef __attribute__((ext_vector_type(4))) unsigned uint4v;
typedef __attribute__((address_space(3))) void* as3p;
typedef const __attribute__((address_space(1))) void* as1p;

#define BLOCK 64
#define NT 4   // 64-row tiles per wave

__device__ __forceinline__ unsigned fbits(float x) {
    return __builtin_bit_cast(unsigned, x);
}
__device__ __forceinline__ float asf(unsigned u) {
    return __builtin_bit_cast(float, u);
}
// (hi16(ub)<<16) | hi16(ua)  -- one v_perm_b32
__device__ __forceinline__ unsigned packhi(unsigned ua, unsigned ub) {
    return __builtin_amdgcn_perm(ub, ua, 0x07060302u);
}
// 8 floats -> 8 truncated bf16 (element j = k-index j)
__device__ __forceinline__ short8 mk_hi(const float* f) {
    uint4v w;
#pragma unroll
    for (int t = 0; t < 4; ++t)
        w[t] = packhi(fbits(f[2 * t]), fbits(f[2 * t + 1]));
    return __builtin_bit_cast(short8, w);
}
// 8 floats -> bf16 of the truncation residuals
__device__ __forceinline__ short8 mk_lo(const float* f) {
    uint4v w;
#pragma unroll
    for (int t = 0; t < 4; ++t) {
        const float la = f[2 * t]     - asf(fbits(f[2 * t])     & 0xFFFF0000u);
        const float lb = f[2 * t + 1] - asf(fbits(f[2 * t + 1]) & 0xFFFF0000u);
        w[t] = packhi(fbits(la), fbits(lb));
    }
    return __builtin_bit_cast(short8, w);
}
#define MFMA(A, B, C) __builtin_amdgcn_mfma_f32_32x32x16_bf16(A, B, C, 0, 0, 0)

template <int IN, int OUT, bool RELU>
__device__ __forceinline__ void layer(const float* __restrict__ W,
                                      const float* __restrict__ b,
                                      const float* h_in, float* h_out) {
#pragma unroll
    for (int o = 0; o < OUT; ++o) h_out[o] = b[o];
#pragma unroll
    for (int i = 0; i < IN; ++i) {
        const float v = h_in[i];
#pragma unroll
        for (int o = 0; o < OUT; ++o)
            h_out[o] = fmaf(v, W[i * OUT + o], h_out[o]);   // uniform -> s_load
    }
    if (RELU) {
#pragma unroll
        for (int o = 0; o < OUT; ++o) h_out[o] = fmaxf(h_out[o], 0.0f);
    }
}

__global__ __launch_bounds__(BLOCK, 4) void mlp_kernel(
        const float* __restrict__ x,
        const float* __restrict__ W0, const float* __restrict__ b0,
        const float* __restrict__ W1, const float* __restrict__ b1,
        const float* __restrict__ W2, const float* __restrict__ b2,
        const float* __restrict__ W3, const float* __restrict__ b3,
        const float* __restrict__ W4, const float* __restrict__ b4,
        float* __restrict__ out, int nrows) {
    extern __shared__ char lds[];
    char* buf0 = lds;            // 4KB chunk buffer (even chunks)
    char* buf1 = lds + 4096;     // 4KB chunk buffer (odd chunks)

    const int lane = threadIdx.x;          // 1 wave per block
    const long long row0 = (long long)blockIdx.x * (NT * 64);
    const char* xbase = reinterpret_cast<const char*>(x + row0 * 64);

    // --- R6/R10-proven per-lane staging source offset (inverse swizzle).
    const int hh = lane >> 3;
    const int qq = (lane & 7) ^ hh;
    const int stage_off = (2 * hh + (qq >> 2)) * 256 + (qq & 3) * 16;

    // --- x-fragment LDS read offsets (B operand): lane holds
    //     x[row = lane&31][k = 16c + 8*hA + j] (and row+32 for accB).
    const int r0 = lane & 31;
    const int hA = lane >> 5;
    auto lds_off = [](int r, int u) {
        const int R = r >> 1, p = r & 1;
        return R * 128 + (((u + 4 * p) ^ (R & 7)) << 4);
    };
    const int aoff0 = lds_off(r0, 2 * hA);
    const int aoff1 = lds_off(r0, 2 * hA + 1);
    const int aoff2 = lds_off(r0 + 32, 2 * hA);
    const int aoff3 = lds_off(r0 + 32, 2 * hA + 1);

    // --- W0^T fragments (A operand), built once, held in registers.
    //     A[row = o = lane&31][k = 16c + 8*hA + j] = W0[k][o].
    const int colB = lane & 31;
    short8 W0h_, W0l_, W1h_, W1l_, W2h_, W2l_, W3h_, W3l_;
    {
        float wf[8];
#define LOADB(c, BH, BL)                                                \
        {                                                               \
            _Pragma("unroll")                                           \
            for (int j = 0; j < 8; ++j)                                 \
                wf[j] = W0[((c) * 16 + 8 * hA + j) * 32 + colB];        \
            BH = mk_hi(wf);                                             \
            BL = mk_lo(wf);                                             \
        }
        LOADB(0, W0h_, W0l_)
        LOADB(1, W1h_, W1l_)
        LOADB(2, W2h_, W2l_)
        LOADB(3, W3h_, W3l_)
#undef LOADB
    }

    // Stage global chunk gc (tile gc>>2, col-chunk gc&3) into buf.
    auto STAGE = [&](int gc, char* buf) {
        const char* s0 = xbase + (gc >> 2) * (64 * 256) + (gc & 3) * 64 +
                         stage_off;
#pragma unroll
        for (int k = 0; k < 4; ++k)
            __builtin_amdgcn_global_load_lds((as1p)(s0 + k * 4096),
                                             (as3p)(buf + k * 1024), 16, 0, 0);
    };

    STAGE(0, buf0);   // prologue

#pragma unroll 1
    for (int tt = 0; tt < NT; ++tt) {
        f32x16 accA, accB;   // D'[o][r]: cols r = batch rows (accA: 0-31)
#pragma unroll
        for (int r = 0; r < 16; ++r) { accA[r] = 0.0f; accB[r] = 0.0f; }

#define CHUNK_BODY(CUR, WH, WL)                                            \
        {                                                                  \
            float fA[8], fB[8];                                            \
            const float4 q0 = *reinterpret_cast<const float4*>(CUR + aoff0); \
            const float4 q1 = *reinterpret_cast<const float4*>(CUR + aoff1); \
            const float4 q2 = *reinterpret_cast<const float4*>(CUR + aoff2); \
            const float4 q3 = *reinterpret_cast<const float4*>(CUR + aoff3); \
            fA[0]=q0.x; fA[1]=q0.y; fA[2]=q0.z; fA[3]=q0.w;                \
            fA[4]=q1.x; fA[5]=q1.y; fA[6]=q1.z; fA[7]=q1.w;                \
            fB[0]=q2.x; fB[1]=q2.y; fB[2]=q2.z; fB[3]=q2.w;                \
            fB[4]=q3.x; fB[5]=q3.y; fB[6]=q3.z; fB[7]=q3.w;                \
            const short8 Xh = mk_hi(fA), Xl = mk_lo(fA);                   \
            const short8 Yh = mk_hi(fB), Yl = mk_lo(fB);                   \
            accA = MFMA(WH, Xh, accA);                                     \
            accA = MFMA(WL, Xh, accA);                                     \
            accA = MFMA(WH, Xl, accA);                                     \
            accB = MFMA(WH, Yh, accB);                                     \
            accB = MFMA(WL, Yh, accB);                                     \
            accB = MFMA(WH, Yl, accB);                                     \
        }
#define PHASE(c, WH, WL)                                                   \
        {                                                                  \
            const int gc = tt * 4 + (c);                                   \
            char* cur = ((c) & 1) ? buf1 : buf0;                           \
            char* oth = ((c) & 1) ? buf0 : buf1;                           \
            if (gc + 1 < NT * 4) {                                         \
                STAGE(gc + 1, oth);                                        \
                asm volatile("s_waitcnt vmcnt(4)" ::: "memory");           \
            } else {                                                       \
                asm volatile("s_waitcnt vmcnt(0)" ::: "memory");           \
            }                                                              \
            __builtin_amdgcn_sched_barrier(0);                             \
            CHUNK_BODY(cur, WH, WL)                                        \
        }

        PHASE(0, W0h_, W0l_)
        PHASE(1, W1h_, W1l_)
        PHASE(2, W2h_, W2l_)
        PHASE(3, W3h_, W3l_)
#undef PHASE
#undef CHUNK_BODY

        // --- Align feature halves with permlane32_swap (a.hi <-> b.lo):
        //     after swap, a[reg] = h0[myrow][f0], b[reg] = h0[myrow][f0+4],
        //     f0 = (reg&3) + 8*(reg>>2), for EVERY lane (myrow = row0+tt*64
        //     + lane). Bias + ReLU applied in-register. No LDS transpose.
        float xr[32];
#pragma unroll
        for (int reg = 0; reg < 16; ++reg) {
            float a = accA[reg];
            float b = accB[reg];
            asm("v_permlane32_swap_b32 %0, %1" : "+v"(a), "+v"(b));
            const int f0 = (reg & 3) + 8 * (reg >> 2);
            xr[f0]     = fmaxf(a + b0[f0],     0.0f);
            xr[f0 + 4] = fmaxf(b + b0[f0 + 4], 0.0f);
        }

        // Tail layers (next tile's chunk-0 DMA is in flight during these).
        float h1[12], h2[8], h3[6], h4[2];
        layer<32, 12, true>(W1, b1, xr, h1);
        layer<12, 8, true>(W2, b2, h1, h2);
        layer<8, 6, true>(W3, b3, h2, h3);
        layer<6, 2, false>(W4, b4, h3, h4);

        reinterpret_cast<float2*>(out)[row0 + tt * 64 + lane] =
            make_float2(h4[0], h4[1]);
    }
}

extern "C" void kernel_launch(void* const* d_in, const int* in_sizes, int n_in,
                              void* d_out, int out_size, void* d_ws, size_t ws_size,
                              hipStream_t stream) {
    const float* x  = (const float*)d_in[0];
    const float* W0 = (const float*)d_in[1];
    const float* b0 = (const float*)d_in[2];
    const float* W1 = (const float*)d_in[3];
    const float* b1 = (const float*)d_in[4];
    const float* W2 = (const float*)d_in[5];
    const float* b2 = (const float*)d_in[6];
    const float* W3 = (const float*)d_in[7];
    const float* b3 = (const float*)d_in[8];
    const float* W4 = (const float*)d_in[9];
    const float* b4 = (const float*)d_in[10];
    float* out = (float*)d_out;

    const int nrows = in_sizes[0] / 64;                 // 1,048,576
    const int rows_per_block = NT * 64;                 // 256
    const int grid = nrows / rows_per_block;            // 4096 (exact)
    const size_t shmem = 8192;                          // 2 x 4KB dbuf only

    mlp_kernel<<<grid, BLOCK, shmem, stream>>>(x, W0, b0, W1, b1, W2, b2,
                                               W3, b3, W4, b4, out, nrows);
}

// Round 16
// 66.250 us; speedup vs baseline: 2.0870x; 1.0087x over previous
//
#include <hip/hip_runtime.h>

// 5-layer MLP [B,64]->32->12->8->6->2, fp32 in/out.
// Layer 0 on matrix cores, TRANSPOSED (D' = W0^T x x^T) via
// v_mfma_f32_32x32x16_bf16, 3-pass truncated-bf16 split; feature halves
// aligned with v_permlane32_swap_b32 (R15-proven, no LDS transpose).
// R16: chunk = 64 rows x 128B (FULL L2 lines) staged as two back-to-back
// R6-swizzled 4KB subchunks (8 global_load_lds per STAGE) -> no line-split
// refetch across phases. Double-buffered 16KB/wave, counted vmcnt(8),
// wave-private LDS, no __syncthreads. Tail layers scalar fmaf (s_load).

typedef __attribute__((ext_vector_type(8))) short short8;
typedef __attribute__((ext_vector_type(16))) float f32x16;
typedef __attribute__((ext_vector_type(4))) unsigned uint4v;
typedef __attribute__((address_space(3))) void* as3p;
typedef const __attribute__((address_space(1))) void* as1p;

#define BLOCK 64
#define NT 4   // 64-row tiles per wave; 2 chunk-phases per tile

__device__ __forceinline__ unsigned fbits(float x) {
    return __builtin_bit_cast(unsigned, x);
}
__device__ __forceinline__ float asf(unsigned u) {
    return __builtin_bit_cast(float, u);
}
// (hi16(ub)<<16) | hi16(ua)  -- one v_perm_b32
__device__ __forceinline__ unsigned packhi(unsigned ua, unsigned ub) {
    return __builtin_amdgcn_perm(ub, ua, 0x07060302u);
}
// 8 floats -> 8 truncated bf16 (element j = k-index j)
__device__ __forceinline__ short8 mk_hi(const float* f) {
    uint4v w;
#pragma unroll
    for (int t = 0; t < 4; ++t)
        w[t] = packhi(fbits(f[2 * t]), fbits(f[2 * t + 1]));
    return __builtin_bit_cast(short8, w);
}
// 8 floats -> bf16 of the truncation residuals
__device__ __forceinline__ short8 mk_lo(const float* f) {
    uint4v w;
#pragma unroll
    for (int t = 0; t < 4; ++t) {
        const float la = f[2 * t]     - asf(fbits(f[2 * t])     & 0xFFFF0000u);
        const float lb = f[2 * t + 1] - asf(fbits(f[2 * t + 1]) & 0xFFFF0000u);
        w[t] = packhi(fbits(la), fbits(lb));
    }
    return __builtin_bit_cast(short8, w);
}
#define MFMA(A, B, C) __builtin_amdgcn_mfma_f32_32x32x16_bf16(A, B, C, 0, 0, 0)

template <int IN, int OUT, bool RELU>
__device__ __forceinline__ void layer(const float* __restrict__ W,
                                      const float* __restrict__ b,
                                      const float* h_in, float* h_out) {
#pragma unroll
    for (int o = 0; o < OUT; ++o) h_out[o] = b[o];
#pragma unroll
    for (int i = 0; i < IN; ++i) {
        const float v = h_in[i];
#pragma unroll
        for (int o = 0; o < OUT; ++o)
            h_out[o] = fmaf(v, W[i * OUT + o], h_out[o]);   // uniform -> s_load
    }
    if (RELU) {
#pragma unroll
        for (int o = 0; o < OUT; ++o) h_out[o] = fmaxf(h_out[o], 0.0f);
    }
}

__global__ __launch_bounds__(BLOCK, 2) void mlp_kernel(
        const float* __restrict__ x,
        const float* __restrict__ W0, const float* __restrict__ b0,
        const float* __restrict__ W1, const float* __restrict__ b1,
        const float* __restrict__ W2, const float* __restrict__ b2,
        const float* __restrict__ W3, const float* __restrict__ b3,
        const float* __restrict__ W4, const float* __restrict__ b4,
        float* __restrict__ out, int nrows) {
    extern __shared__ char lds[];
    char* buf0 = lds;            // 8KB chunk buffer (even chunks)
    char* buf1 = lds + 8192;     // 8KB chunk buffer (odd chunks)

    const int lane = threadIdx.x;          // 1 wave per block
    const long long row0 = (long long)blockIdx.x * (NT * 64);
    const char* xbase = reinterpret_cast<const char*>(x + row0 * 64);

    // --- R6/R10-proven per-lane staging source offset (inverse swizzle).
    const int hh = lane >> 3;
    const int qq = (lane & 7) ^ hh;
    const int stage_off = (2 * hh + (qq >> 2)) * 256 + (qq & 3) * 16;

    // --- x-fragment LDS read offsets (B operand): within a 4KB subchunk,
    //     lane holds x[row = lane&31][8*hA .. 8*hA+7] (and row+32).
    const int r0 = lane & 31;
    const int hA = lane >> 5;
    auto lds_off = [](int r, int u) {
        const int R = r >> 1, p = r & 1;
        return R * 128 + (((u + 4 * p) ^ (R & 7)) << 4);
    };
    const int aoff0 = lds_off(r0, 2 * hA);
    const int aoff1 = lds_off(r0, 2 * hA + 1);
    const int aoff2 = lds_off(r0 + 32, 2 * hA);
    const int aoff3 = lds_off(r0 + 32, 2 * hA + 1);

    // --- W0^T fragments (A operand), built once, held in registers.
    //     k-step s: A[o = lane&31][k = 16s + 8*hA + j] = W0[k][o].
    const int colB = lane & 31;
    short8 W0h_, W0l_, W1h_, W1l_, W2h_, W2l_, W3h_, W3l_;
    {
        float wf[8];
#define LOADB(s, BH, BL)                                                \
        {                                                               \
            _Pragma("unroll")                                           \
            for (int j = 0; j < 8; ++j)                                 \
                wf[j] = W0[((s) * 16 + 8 * hA + j) * 32 + colB];        \
            BH = mk_hi(wf);                                             \
            BL = mk_lo(wf);                                             \
        }
        LOADB(0, W0h_, W0l_)
        LOADB(1, W1h_, W1l_)
        LOADB(2, W2h_, W2l_)
        LOADB(3, W3h_, W3l_)
#undef LOADB
    }

    // Stage global chunk gc (tile gc>>1, 128B-col gc&1) into buf:
    // two R6 4KB subchunks staged BACK-TO-BACK -> each 128B line is
    // consumed by consecutive instructions (no cross-phase line split).
    auto STAGE8 = [&](int gc, char* buf) {
        const char* s0 = xbase + (gc >> 1) * (64 * 256) + (gc & 1) * 128 +
                         stage_off;
#pragma unroll
        for (int k = 0; k < 4; ++k)
            __builtin_amdgcn_global_load_lds((as1p)(s0 + k * 4096),
                                             (as3p)(buf + k * 1024), 16, 0, 0);
#pragma unroll
        for (int k = 0; k < 4; ++k)
            __builtin_amdgcn_global_load_lds((as1p)(s0 + 64 + k * 4096),
                                             (as3p)(buf + 4096 + k * 1024),
                                             16, 0, 0);
    };

    STAGE8(0, buf0);   // prologue

#pragma unroll 1
    for (int tt = 0; tt < NT; ++tt) {
        f32x16 accA, accB;   // D'[o][r]: cols r = batch rows (accA: 0-31)
#pragma unroll
        for (int r = 0; r < 16; ++r) { accA[r] = 0.0f; accB[r] = 0.0f; }

// One K=16 step from a 4KB subchunk at CUR (+SUB byte offset).
#define KSTEP(CUR, SUB, WH, WL)                                            \
        {                                                                  \
            float fA[8], fB[8];                                            \
            const float4 q0 = *reinterpret_cast<const float4*>(CUR + SUB + aoff0); \
            const float4 q1 = *reinterpret_cast<const float4*>(CUR + SUB + aoff1); \
            const float4 q2 = *reinterpret_cast<const float4*>(CUR + SUB + aoff2); \
            const float4 q3 = *reinterpret_cast<const float4*>(CUR + SUB + aoff3); \
            fA[0]=q0.x; fA[1]=q0.y; fA[2]=q0.z; fA[3]=q0.w;                \
            fA[4]=q1.x; fA[5]=q1.y; fA[6]=q1.z; fA[7]=q1.w;                \
            fB[0]=q2.x; fB[1]=q2.y; fB[2]=q2.z; fB[3]=q2.w;                \
            fB[4]=q3.x; fB[5]=q3.y; fB[6]=q3.z; fB[7]=q3.w;                \
            const short8 Xh = mk_hi(fA), Xl = mk_lo(fA);                   \
            const short8 Yh = mk_hi(fB), Yl = mk_lo(fB);                   \
            accA = MFMA(WH, Xh, accA);                                     \
            accA = MFMA(WL, Xh, accA);                                     \
            accA = MFMA(WH, Xl, accA);                                     \
            accB = MFMA(WH, Yh, accB);                                     \
            accB = MFMA(WL, Yh, accB);                                     \
            accB = MFMA(WH, Yl, accB);                                     \
        }
#define PHASE(c, WH0, WL0, WH1, WL1)                                       \
        {                                                                  \
            const int gc = tt * 2 + (c);                                   \
            char* cur = ((c) & 1) ? buf1 : buf0;                           \
            char* oth = ((c) & 1) ? buf0 : buf1;                           \
            if (gc + 1 < NT * 2) {                                         \
                STAGE8(gc + 1, oth);                                       \
                asm volatile("s_waitcnt vmcnt(8)" ::: "memory");           \
            } else {                                                       \
                asm volatile("s_waitcnt vmcnt(0)" ::: "memory");           \
            }                                                              \
            __builtin_amdgcn_sched_barrier(0);                             \
            KSTEP(cur, 0,    WH0, WL0)                                     \
            KSTEP(cur, 4096, WH1, WL1)                                     \
        }

        PHASE(0, W0h_, W0l_, W1h_, W1l_)
        PHASE(1, W2h_, W2l_, W3h_, W3l_)
#undef PHASE
#undef KSTEP

        // --- Align feature halves with permlane32_swap; bias+ReLU in-reg.
        float xr[32];
#pragma unroll
        for (int reg = 0; reg < 16; ++reg) {
            float a = accA[reg];
            float b = accB[reg];
            asm("v_permlane32_swap_b32 %0, %1" : "+v"(a), "+v"(b));
            const int f0 = (reg & 3) + 8 * (reg >> 2);
            xr[f0]     = fmaxf(a + b0[f0],     0.0f);
            xr[f0 + 4] = fmaxf(b + b0[f0 + 4], 0.0f);
        }

        // Tail layers (next tile's chunk-0 DMA is in flight during these).
        float h1[12], h2[8], h3[6], h4[2];
        layer<32, 12, true>(W1, b1, xr, h1);
        layer<12, 8, true>(W2, b2, h1, h2);
        layer<8, 6, true>(W3, b3, h2, h3);
        layer<6, 2, false>(W4, b4, h3, h4);

        reinterpret_cast<float2*>(out)[row0 + tt * 64 + lane] =
            make_float2(h4[0], h4[1]);
    }
}

extern "C" void kernel_launch(void* const* d_in, const int* in_sizes, int n_in,
                              void* d_out, int out_size, void* d_ws, size_t ws_size,
                              hipStream_t stream) {
    const float* x  = (const float*)d_in[0];
    const float* W0 = (const float*)d_in[1];
    const float* b0 = (const float*)d_in[2];
    const float* W1 = (const float*)d_in[3];
    const float* b1 = (const float*)d_in[4];
    const float* W2 = (const float*)d_in[5];
    const float* b2 = (const float*)d_in[6];
    const float* W3 = (const float*)d_in[7];
    const float* b3 = (const float*)d_in[8];
    const float* W4 = (const float*)d_in[9];
    const float* b4 = (const float*)d_in[10];
    float* out = (float*)d_out;

    const int nrows = in_sizes[0] / 64;                 // 1,048,576
    const int rows_per_block = NT * 64;                 // 256
    const int grid = nrows / rows_per_block;            // 4096 (exact)
    const size_t shmem = 16384;                         // 2 x 8KB dbuf

    mlp_kernel<<<grid, BLOCK, shmem, stream>>>(x, W0, b0, W1, b1, W2, b2,
                                               W3, b3, W4, b4, out, nrows);
}